// Round 8
// baseline (340.057 us; speedup 1.0000x reference)
//
#include <hip/hip_runtime.h>
#include <hip/hip_bf16.h>
#include <math.h>

#define N_NODES 50000
#define N_EDGES 800000
#define EP (N_EDGES + N_NODES)   /* 850000 edges incl. self-loops */
#define HID 64
#define HEADS 4
#define F1 (HEADS * HID)         /* 256 */
#define NC 16
#define SLOPE 0.2f
#define CH1 256                  /* edge chunk (layer 1) */
#define G1B 1024                 /* gemm grid blocks */
#define NT 49                    /* scan tiles = ceil(N/1024) */

// ---- bf16 helpers (round-to-nearest-even pack, exact unpack) ----
__device__ __forceinline__ unsigned short bf16rn(float f) {
    unsigned u = __float_as_uint(f);
    return (unsigned short)((u + 0x7fffu + ((u >> 16) & 1u)) >> 16);
}
__device__ __forceinline__ float bf_lo(unsigned p) { return __uint_as_float(p << 16); }
__device__ __forceinline__ float bf_hi(unsigned p) { return __uint_as_float(p & 0xffff0000u); }

__device__ __forceinline__ void edge_sd(int e, const int* __restrict__ ei, int& s, int& d) {
    if (e < N_EDGES) { s = ei[e]; d = ei[N_EDGES + e]; }
    else             { s = e - N_EDGES; d = s; }
}

// tile-local exclusive scan: 49 blocks x 1024 threads, 1024 elems/block
__global__ __launch_bounds__(1024) void k_scan_local(const int* __restrict__ cnt,
        int* __restrict__ lexcl, int* __restrict__ bsum) {
    __shared__ int wsum[16];
    int t = threadIdx.x, lane = t & 63, wid = t >> 6;
    int i = blockIdx.x * 1024 + t;
    int v = (i < N_NODES) ? cnt[i] : 0;
    int s = v;
#pragma unroll
    for (int off = 1; off < 64; off <<= 1) {
        int x = __shfl_up(s, off);
        if (lane >= off) s += x;
    }
    if (lane == 63) wsum[wid] = s;
    __syncthreads();
    if (t < 16) {
        int w = wsum[t];
#pragma unroll
        for (int off = 1; off < 16; off <<= 1) {
            int x = __shfl_up(w, off);
            if (t >= off) w += x;
        }
        wsum[t] = w;
    }
    __syncthreads();
    int waveoff = (wid == 0) ? 0 : wsum[wid - 1];
    int incl = s + waveoff;
    if (i < N_NODES) lexcl[i] = incl - v;
    if (t == 1023) bsum[blockIdx.x] = incl;
}

// fused top-scan + add: every block redundantly scans the 49 block sums (cheap)
__global__ __launch_bounds__(256) void k_scan_add(int* __restrict__ row_start,
        const int* __restrict__ bsum, int* __restrict__ cursor) {
    __shared__ int sb[64];
    __shared__ int stot;
    int t = threadIdx.x;
    if (t < 64) {
        int v = (t < NT) ? bsum[t] : 0;
        int s = v;
#pragma unroll
        for (int off = 1; off < 64; off <<= 1) {
            int x = __shfl_up(s, off);
            if (t >= off) s += x;
        }
        sb[t] = s - v;
        if (t == 63) stot = s;
    }
    __syncthreads();
    int i = blockIdx.x * 256 + t;
    if (i < N_NODES) {
        int v = row_start[i] + sb[i >> 10];
        row_start[i] = v;
        cursor[i] = v;
    }
    if (i == 0) row_start[N_NODES] = stot;
}

__global__ void k_scatter(const int* __restrict__ ei, int* __restrict__ cursor,
                          int* __restrict__ esrc) {
    int e = blockIdx.x * blockDim.x + threadIdx.x;
    if (e >= EP) return;
    int s, d; edge_sd(e, ei, s, d);
    int p = atomicAdd(&cursor[d], 1);
    esrc[p] = s;
}

// ------- layer 1 GEMM (weight-stationary) + fused edge histogram -------
__global__ __launch_bounds__(256) void k_gemm1(
        const float* __restrict__ x, const float* __restrict__ W1,
        const float* __restrict__ att_s, const float* __restrict__ att_d,
        unsigned short* __restrict__ xh1b, float* __restrict__ a_src, float* __restrict__ a_dst,
        const int* __restrict__ ei, int* __restrict__ cnt) {
    // fused histogram (independent work; atomics drain behind the GEMM)
    for (int e = blockIdx.x * 256 + threadIdx.x; e < EP; e += 256 * G1B) {
        int s, d; edge_sd(e, ei, s, d);
        atomicAdd(&cnt[d], 1);
    }
    int t = threadIdx.x;                  // output column
    float w[HID];
#pragma unroll
    for (int k = 0; k < HID; ++k) w[k] = W1[k * F1 + t];
    float as_ = att_s[t], ad_ = att_d[t];
    __shared__ float xs[8][HID];
    int b = blockIdx.x;
    for (int i0 = 0; i0 < 49; i0 += 8) {
        __syncthreads();
        int col = t & 63;
#pragma unroll
        for (int half = 0; half < 2; ++half) {
            int rr = (t >> 6) + half * 4;
            int r = b + (i0 + rr) * G1B;
            if (r < N_NODES) xs[rr][col] = x[(size_t)r * HID + col];
        }
        __syncthreads();
#pragma unroll
        for (int rr = 0; rr < 8; ++rr) {
            int r = b + (i0 + rr) * G1B;
            if (r >= N_NODES) continue;
            const float4* xr = (const float4*)xs[rr];
            float acc = 0.0f;
#pragma unroll
            for (int q = 0; q < 16; ++q) {
                float4 xv = xr[q];
                acc += w[4*q] * xv.x + w[4*q+1] * xv.y + w[4*q+2] * xv.z + w[4*q+3] * xv.w;
            }
            xh1b[(size_t)r * F1 + t] = bf16rn(acc);
            float ps = acc * as_, pd = acc * ad_;
#pragma unroll
            for (int o = 32; o >= 1; o >>= 1) {
                ps += __shfl_xor(ps, o);
                pd += __shfl_xor(pd, o);
            }
            if ((t & 63) == 0) {
                int h = t >> 6;
                a_src[r * HEADS + h] = ps;
                a_dst[r * HEADS + h] = pd;
            }
        }
    }
}

// ------- layer 1 fused: online-max softmax + aggregate + bias + ELU + (h @ W2) -------
// W2 preloaded into wave-0 VGPRs at block start (loads drain behind the gather loop)
__global__ __launch_bounds__(128) void k_csr1(
        const int* __restrict__ row_start, const int* __restrict__ esrc,
        const float* __restrict__ a_src, const float* __restrict__ a_dst,
        const unsigned short* __restrict__ xh1b, const float* __restrict__ b1,
        const float* __restrict__ W2, const float* __restrict__ att_s2,
        const float* __restrict__ att_d2,
        unsigned short* __restrict__ xh2b, float* __restrict__ a_src2,
        float* __restrict__ a_dst2) {
    int d = blockIdx.x;
    int t = threadIdx.x, l = t & 31, g = t >> 5;
    int base = row_start[d], deg = row_start[d + 1] - base;
    __shared__ int   ls[CH1];
    __shared__ float lal[HEADS][CH1];
    // preload W2 fragment (wave 0 only; wave-uniform branch)
    float4 wreg[16];
    if (t < 64) {
        const float4* w4 = (const float4*)W2;
#pragma unroll
        for (int j = 0; j < 16; ++j) wreg[j] = w4[t + 64 * j];
    }
    float adh = a_dst[d * HEADS + g];
    float m = -1e30f, den = 0.0f, acc0 = 0.0f, acc1 = 0.0f;
    for (int c0 = 0; c0 < deg; c0 += CH1) {
        int cn = min(CH1, deg - c0);
        for (int j = t; j < cn; j += 128) ls[j] = esrc[base + c0 + j];
        __syncthreads();
        float cm = -1e30f;
        for (int j = l; j < cn; j += 32) {
            float ev = a_src[ls[j] * HEADS + g] + adh;
            ev = ev > 0.0f ? ev : SLOPE * ev;
            lal[g][j] = ev;
            cm = fmaxf(cm, ev);
        }
#pragma unroll
        for (int o = 16; o >= 1; o >>= 1) cm = fmaxf(cm, __shfl_xor(cm, o));
        float mn = fmaxf(m, cm);
        float sc = expf(m - mn);
        acc0 *= sc; acc1 *= sc; den *= sc; m = mn;
        float cs = 0.0f;
        for (int j = l; j < cn; j += 32) {
            float wj = expf(lal[g][j] - m);
            lal[g][j] = wj;
            cs += wj;
        }
#pragma unroll
        for (int o = 16; o >= 1; o >>= 1) cs += __shfl_xor(cs, o);
        den += cs;
        // aggregate this chunk: bf16 row gather, 2 features/thread, 2 edges in flight
        int j = 0;
        for (; j + 1 < cn; j += 2) {
            float w0 = lal[g][j], w1 = lal[g][j + 1];
            unsigned p0 = *(const unsigned*)(xh1b + (size_t)ls[j]     * F1 + 2 * t);
            unsigned p1 = *(const unsigned*)(xh1b + (size_t)ls[j + 1] * F1 + 2 * t);
            acc0 += w0 * bf_lo(p0); acc1 += w0 * bf_hi(p0);
            acc0 += w1 * bf_lo(p1); acc1 += w1 * bf_hi(p1);
        }
        if (j < cn) {
            float w0 = lal[g][j];
            unsigned p0 = *(const unsigned*)(xh1b + (size_t)ls[j] * F1 + 2 * t);
            acc0 += w0 * bf_lo(p0); acc1 += w0 * bf_hi(p0);
        }
        __syncthreads();
    }
    float inv = 1.0f / (den + 1e-16f);
    float2 bb = *(const float2*)(b1 + 2 * t);
    float v0 = acc0 * inv + bb.x;
    float v1 = acc1 * inv + bb.y;
    v0 = v0 > 0.0f ? v0 : (expf(v0) - 1.0f);
    v1 = v1 > 0.0f ? v1 : (expf(v1) - 1.0f);
    // ---- stage h row in LDS (reuse lal[0]; barrier guards cross-wave WAR) ----
    float* hrow = &lal[0][0];
    __syncthreads();
    hrow[2 * t] = v0; hrow[2 * t + 1] = v1;
    __syncthreads();
    if (t < 64) {
        int k0 = t >> 2;                          // h-row base (stride 16)
        int cg = (t & 3) * 4;                     // class-group base
        float a0 = 0.0f, a1 = 0.0f, a2 = 0.0f, a3 = 0.0f;
#pragma unroll
        for (int j = 0; j < 16; ++j) {
            float hk = hrow[k0 + 16 * j];         // 16-addr broadcast, conflict-free
            float4 wv = wreg[j];                  // in-register W2
            a0 += hk * wv.x; a1 += hk * wv.y; a2 += hk * wv.z; a3 += hk * wv.w;
        }
#pragma unroll
        for (int o = 4; o <= 32; o <<= 1) {       // reduce lanes sharing (t&3)
            a0 += __shfl_xor(a0, o); a1 += __shfl_xor(a1, o);
            a2 += __shfl_xor(a2, o); a3 += __shfl_xor(a3, o);
        }
        if (t < 4) {                              // lane t owns classes 4t..4t+3
            unsigned u0 = (unsigned)bf16rn(a0) | ((unsigned)bf16rn(a1) << 16);
            unsigned u1 = (unsigned)bf16rn(a2) | ((unsigned)bf16rn(a3) << 16);
            *(uint2*)(xh2b + (size_t)d * NC + 4 * t) = make_uint2(u0, u1);
            float ps = a0 * att_s2[cg] + a1 * att_s2[cg + 1]
                     + a2 * att_s2[cg + 2] + a3 * att_s2[cg + 3];
            float pd = a0 * att_d2[cg] + a1 * att_d2[cg + 1]
                     + a2 * att_d2[cg + 2] + a3 * att_d2[cg + 3];
            ps += __shfl_xor(ps, 1); ps += __shfl_xor(ps, 2);
            pd += __shfl_xor(pd, 1); pd += __shfl_xor(pd, 2);
            if (t == 0) { a_src2[d] = ps; a_dst2[d] = pd; }
        }
    }
}

// ------- layer 2 fused: softmax(no-max) + aggregate + bias + log_softmax -------
// 4 waves/block, 1 dst node per wave; 2 classes/lane (uint bf16x2 gather),
// 8 edges in flight per wave
__global__ __launch_bounds__(256) void k_csr2(
        const int* __restrict__ row_start, const int* __restrict__ esrc,
        const float* __restrict__ a_src2, const float* __restrict__ a_dst2,
        const unsigned short* __restrict__ xh2b, const float* __restrict__ b2,
        float* __restrict__ out) {
    int w = threadIdx.x >> 6, l = threadIdx.x & 63;
    int d = blockIdx.x * 4 + w;
    if (d >= N_NODES) return;
    int base = row_start[d], deg = row_start[d + 1] - base;
    __shared__ int   ls[4][64];
    __shared__ float lal[4][64];
    float adh = a_dst2[d];
    int cp = l & 7, je = l >> 3;
    float denl = 0.0f, acc0 = 0.0f, acc1 = 0.0f;
    for (int c0 = 0; c0 < deg; c0 += 64) {
        int cn = min(64, deg - c0);
        if (l < cn) {
            int s = esrc[base + c0 + l];
            ls[w][l] = s;
            float ev = a_src2[s] + adh;
            ev = ev > 0.0f ? ev : SLOPE * ev;
            float wj = __expf(ev);
            lal[w][l] = wj;          // same-wave RAW below
            denl += wj;
        }
        for (int j = je; j < cn; j += 8) {
            float wj = lal[w][j];
            unsigned pv = *(const unsigned*)(xh2b + (size_t)ls[w][j] * NC + 2 * cp);
            acc0 += wj * bf_lo(pv);
            acc1 += wj * bf_hi(pv);
        }
    }
#pragma unroll
    for (int o = 32; o >= 1; o >>= 1) denl += __shfl_xor(denl, o);
#pragma unroll
    for (int o = 8; o <= 32; o <<= 1) {           // reduce over the 8 je slots
        acc0 += __shfl_xor(acc0, o);
        acc1 += __shfl_xor(acc1, o);
    }
    float inv = 1.0f / (denl + 1e-16f);
    float v0 = acc0 * inv + b2[2 * cp];
    float v1 = acc1 * inv + b2[2 * cp + 1];
    float mm = fmaxf(v0, v1);
#pragma unroll
    for (int o = 1; o <= 4; o <<= 1) mm = fmaxf(mm, __shfl_xor(mm, o));
    float se = __expf(v0 - mm) + __expf(v1 - mm);
#pragma unroll
    for (int o = 1; o <= 4; o <<= 1) se += __shfl_xor(se, o);
    float lse = mm + logf(se);
    if (l < 8) *(float2*)(out + (size_t)d * NC + 2 * cp) = make_float2(v0 - lse, v1 - lse);
}

extern "C" void kernel_launch(void* const* d_in, const int* in_sizes, int n_in,
                              void* d_out, int out_size, void* d_ws, size_t ws_size,
                              hipStream_t stream) {
    const float* x        = (const float*)d_in[0];
    const int*   ei       = (const int*)d_in[1];
    const float* W1       = (const float*)d_in[2];
    const float* att_src1 = (const float*)d_in[3];
    const float* att_dst1 = (const float*)d_in[4];
    const float* b1       = (const float*)d_in[5];
    const float* W2       = (const float*)d_in[6];
    const float* att_src2 = (const float*)d_in[7];
    const float* att_dst2 = (const float*)d_in[8];
    const float* b2       = (const float*)d_in[9];
    float* out = (float*)d_out;

    // ---- workspace layout ----
    char* p = (char*)d_ws;
    unsigned short* xh1b  = (unsigned short*)p; p += (size_t)N_NODES * F1 * 2;   // 25.6MB
    unsigned short* xh2b  = (unsigned short*)p; p += (size_t)N_NODES * NC * 2;   // 1.6MB
    float* a_src1 = (float*)p; p += (size_t)N_NODES * HEADS * 4;
    float* a_dst1 = (float*)p; p += (size_t)N_NODES * HEADS * 4;
    float* a_src2 = (float*)p; p += (size_t)N_NODES * 4;
    float* a_dst2 = (float*)p; p += (size_t)N_NODES * 4;
    int* cnt       = (int*)p;  p += (size_t)N_NODES * 4;
    int* cursor    = (int*)p;  p += (size_t)N_NODES * 4;
    int* row_start = (int*)p;  p += (size_t)(N_NODES + 1) * 4;
    int* bsum      = (int*)p;  p += 64 * 4;
    int* esrc      = (int*)p;  p += (size_t)EP * 4;

    // ---- CSR build (hist fused into gemm1) ----
    hipMemsetAsync(cnt, 0, (size_t)N_NODES * 4, stream);
    k_gemm1<<<G1B, 256, 0, stream>>>(x, W1, att_src1, att_dst1, xh1b, a_src1, a_dst1,
                                     ei, cnt);
    k_scan_local<<<NT, 1024, 0, stream>>>(cnt, row_start, bsum);
    k_scan_add<<<(N_NODES + 255) / 256, 256, 0, stream>>>(row_start, bsum, cursor);
    k_scatter<<<(EP + 255) / 256, 256, 0, stream>>>(ei, cursor, esrc);

    // ---- layer 1 (+ fused layer-2 projection) ----
    k_csr1<<<N_NODES, 128, 0, stream>>>(row_start, esrc, a_src1, a_dst1, xh1b, b1,
                                        W2, att_src2, att_dst2, xh2b, a_src2, a_dst2);

    // ---- layer 2 ----
    k_csr2<<<(N_NODES + 3) / 4, 256, 0, stream>>>(row_start, esrc, a_src2, a_dst2, xh2b, b2, out);
}

// Round 9
// 253.624 us; speedup vs baseline: 1.3408x; 1.3408x over previous
//
#include <hip/hip_runtime.h>
#include <hip/hip_bf16.h>
#include <math.h>

#define N_NODES 50000
#define N_EDGES 800000
#define EP (N_EDGES + N_NODES)   /* 850000 edges incl. self-loops */
#define HID 64
#define HEADS 4
#define F1 (HEADS * HID)         /* 256 */
#define NC 16
#define SLOPE 0.2f
#define G1B 1024                 /* gemm grid blocks */
#define NT 49                    /* scan tiles = ceil(N/1024) */

// ---- bf16 helpers (round-to-nearest-even pack, exact unpack) ----
__device__ __forceinline__ unsigned short bf16rn(float f) {
    unsigned u = __float_as_uint(f);
    return (unsigned short)((u + 0x7fffu + ((u >> 16) & 1u)) >> 16);
}
__device__ __forceinline__ float bf_lo(unsigned p) { return __uint_as_float(p << 16); }
__device__ __forceinline__ float bf_hi(unsigned p) { return __uint_as_float(p & 0xffff0000u); }

__device__ __forceinline__ void edge_sd(int e, const int* __restrict__ ei, int& s, int& d) {
    if (e < N_EDGES) { s = ei[e]; d = ei[N_EDGES + e]; }
    else             { s = e - N_EDGES; d = s; }
}

// tile-local exclusive scan: 49 blocks x 1024 threads, 1024 elems/block
__global__ __launch_bounds__(1024) void k_scan_local(const int* __restrict__ cnt,
        int* __restrict__ lexcl, int* __restrict__ bsum) {
    __shared__ int wsum[16];
    int t = threadIdx.x, lane = t & 63, wid = t >> 6;
    int i = blockIdx.x * 1024 + t;
    int v = (i < N_NODES) ? cnt[i] : 0;
    int s = v;
#pragma unroll
    for (int off = 1; off < 64; off <<= 1) {
        int x = __shfl_up(s, off);
        if (lane >= off) s += x;
    }
    if (lane == 63) wsum[wid] = s;
    __syncthreads();
    if (t < 16) {
        int w = wsum[t];
#pragma unroll
        for (int off = 1; off < 16; off <<= 1) {
            int x = __shfl_up(w, off);
            if (t >= off) w += x;
        }
        wsum[t] = w;
    }
    __syncthreads();
    int waveoff = (wid == 0) ? 0 : wsum[wid - 1];
    int incl = s + waveoff;
    if (i < N_NODES) lexcl[i] = incl - v;
    if (t == 1023) bsum[blockIdx.x] = incl;
}

// fused top-scan + add: every block redundantly scans the 49 block sums (cheap)
__global__ __launch_bounds__(256) void k_scan_add(int* __restrict__ row_start,
        const int* __restrict__ bsum, int* __restrict__ cursor) {
    __shared__ int sb[64];
    __shared__ int stot;
    int t = threadIdx.x;
    if (t < 64) {
        int v = (t < NT) ? bsum[t] : 0;
        int s = v;
#pragma unroll
        for (int off = 1; off < 64; off <<= 1) {
            int x = __shfl_up(s, off);
            if (t >= off) s += x;
        }
        sb[t] = s - v;
        if (t == 63) stot = s;
    }
    __syncthreads();
    int i = blockIdx.x * 256 + t;
    if (i < N_NODES) {
        int v = row_start[i] + sb[i >> 10];
        row_start[i] = v;
        cursor[i] = v;
    }
    if (i == 0) row_start[N_NODES] = stot;
}

__global__ void k_scatter(const int* __restrict__ ei, int* __restrict__ cursor,
                          int* __restrict__ esrc) {
    int e = blockIdx.x * blockDim.x + threadIdx.x;
    if (e >= EP) return;
    int s, d; edge_sd(e, ei, s, d);
    int p = atomicAdd(&cursor[d], 1);
    esrc[p] = s;
}

// ------- layer 1 GEMM (weight-stationary) + fused edge histogram -------
__global__ __launch_bounds__(256) void k_gemm1(
        const float* __restrict__ x, const float* __restrict__ W1,
        const float* __restrict__ att_s, const float* __restrict__ att_d,
        unsigned short* __restrict__ xh1b, float* __restrict__ a_src, float* __restrict__ a_dst,
        const int* __restrict__ ei, int* __restrict__ cnt) {
    // fused histogram (independent work; atomics drain behind the GEMM)
    for (int e = blockIdx.x * 256 + threadIdx.x; e < EP; e += 256 * G1B) {
        int s, d; edge_sd(e, ei, s, d);
        atomicAdd(&cnt[d], 1);
    }
    int t = threadIdx.x;                  // output column
    float w[HID];
#pragma unroll
    for (int k = 0; k < HID; ++k) w[k] = W1[k * F1 + t];
    float as_ = att_s[t], ad_ = att_d[t];
    __shared__ float xs[8][HID];
    int b = blockIdx.x;
    for (int i0 = 0; i0 < 49; i0 += 8) {
        __syncthreads();
        int col = t & 63;
#pragma unroll
        for (int half = 0; half < 2; ++half) {
            int rr = (t >> 6) + half * 4;
            int r = b + (i0 + rr) * G1B;
            if (r < N_NODES) xs[rr][col] = x[(size_t)r * HID + col];
        }
        __syncthreads();
#pragma unroll
        for (int rr = 0; rr < 8; ++rr) {
            int r = b + (i0 + rr) * G1B;
            if (r >= N_NODES) continue;
            const float4* xr = (const float4*)xs[rr];
            float acc = 0.0f;
#pragma unroll
            for (int q = 0; q < 16; ++q) {
                float4 xv = xr[q];
                acc += w[4*q] * xv.x + w[4*q+1] * xv.y + w[4*q+2] * xv.z + w[4*q+3] * xv.w;
            }
            xh1b[(size_t)r * F1 + t] = bf16rn(acc);
            float ps = acc * as_, pd = acc * ad_;
#pragma unroll
            for (int o = 32; o >= 1; o >>= 1) {
                ps += __shfl_xor(ps, o);
                pd += __shfl_xor(pd, o);
            }
            if ((t & 63) == 0) {
                int h = t >> 6;
                a_src[r * HEADS + h] = ps;
                a_dst[r * HEADS + h] = pd;
            }
        }
    }
}

// ------- layer 1, wave-per-node: softmax + aggregate + bias + ELU + (h @ W2) -------
// 256 threads = 4 waves = 4 dst nodes; ZERO barriers (wave-owned LDS slices).
// Gather: lane l owns features 4l..4l+3 (one dwordx2 per edge); head = l>>4.
// Softmax: 16-lane group per head (shfl_xor o<=8 stays in-group).
__global__ __launch_bounds__(256) void k_csr1(
        const int* __restrict__ row_start, const int* __restrict__ esrc,
        const float* __restrict__ a_src, const float* __restrict__ a_dst,
        const unsigned short* __restrict__ xh1b, const float* __restrict__ b1,
        const float* __restrict__ W2, const float* __restrict__ att_s2,
        const float* __restrict__ att_d2,
        unsigned short* __restrict__ xh2b, float* __restrict__ a_src2,
        float* __restrict__ a_dst2) {
    int w = threadIdx.x >> 6, l = threadIdx.x & 63;
    int d = blockIdx.x * 4 + w;
    if (d >= N_NODES) return;
    int base = row_start[d], deg = row_start[d + 1] - base;
    __shared__ int   ls[4][64];
    __shared__ float lal[4][4][64];      // [wave][head][edge]
    int h = l >> 4, e16 = l & 15;
    int* lsw = ls[w];
    float adh = a_dst[d * HEADS + h];
    float m = -1e30f, den = 0.0f;
    float a0 = 0.0f, a1 = 0.0f, a2 = 0.0f, a3 = 0.0f;   // features 4l..4l+3
    for (int c0 = 0; c0 < deg; c0 += 64) {
        int cn = min(64, deg - c0);
        if (l < cn) lsw[l] = esrc[base + c0 + l];
        // ---- softmax phase: 16-lane group per head ----
        float cm = -1e30f;
        for (int j = e16; j < cn; j += 16) {
            float ev = a_src[lsw[j] * HEADS + h] + adh;
            ev = ev > 0.0f ? ev : SLOPE * ev;
            lal[w][h][j] = ev;
            cm = fmaxf(cm, ev);
        }
#pragma unroll
        for (int o = 8; o >= 1; o >>= 1) cm = fmaxf(cm, __shfl_xor(cm, o));
        float mn = fmaxf(m, cm);
        float sc = expf(m - mn);
        a0 *= sc; a1 *= sc; a2 *= sc; a3 *= sc; den *= sc; m = mn;
        float cs = 0.0f;
        for (int j = e16; j < cn; j += 16) {
            float wj = expf(lal[w][h][j] - m);
            lal[w][h][j] = wj;
            cs += wj;
        }
#pragma unroll
        for (int o = 8; o >= 1; o >>= 1) cs += __shfl_xor(cs, o);
        den += cs;
        // ---- gather phase: one dwordx2 per edge per lane, 2 edges in flight ----
        const float* lalh = lal[w][h];
        int j = 0;
        for (; j + 1 < cn; j += 2) {
            float w0 = lalh[j], w1 = lalh[j + 1];
            uint2 p0 = *(const uint2*)(xh1b + (size_t)lsw[j]     * F1 + 4 * l);
            uint2 p1 = *(const uint2*)(xh1b + (size_t)lsw[j + 1] * F1 + 4 * l);
            a0 += w0 * bf_lo(p0.x); a1 += w0 * bf_hi(p0.x);
            a2 += w0 * bf_lo(p0.y); a3 += w0 * bf_hi(p0.y);
            a0 += w1 * bf_lo(p1.x); a1 += w1 * bf_hi(p1.x);
            a2 += w1 * bf_lo(p1.y); a3 += w1 * bf_hi(p1.y);
        }
        if (j < cn) {
            float w0 = lalh[j];
            uint2 p0 = *(const uint2*)(xh1b + (size_t)lsw[j] * F1 + 4 * l);
            a0 += w0 * bf_lo(p0.x); a1 += w0 * bf_hi(p0.x);
            a2 += w0 * bf_lo(p0.y); a3 += w0 * bf_hi(p0.y);
        }
    }
    float inv = 1.0f / (den + 1e-16f);
    float4 bb = *(const float4*)(b1 + 4 * l);
    float v0 = a0 * inv + bb.x;
    float v1 = a1 * inv + bb.y;
    float v2 = a2 * inv + bb.z;
    float v3 = a3 * inv + bb.w;
    v0 = v0 > 0.0f ? v0 : (expf(v0) - 1.0f);
    v1 = v1 > 0.0f ? v1 : (expf(v1) - 1.0f);
    v2 = v2 > 0.0f ? v2 : (expf(v2) - 1.0f);
    v3 = v3 > 0.0f ? v3 : (expf(v3) - 1.0f);
    // ---- stage h row in this wave's LDS slice (all lal reads done; same wave) ----
    float* hrow = &lal[w][0][0];          // 256 floats
    *(float4*)(hrow + 4 * l) = make_float4(v0, v1, v2, v3);
    // ---- projection: flat coalesced W2 (16KB; L1-resident after first wave) ----
    int k0 = l >> 2;                      // h index base (stride 16)
    int cg = (l & 3) * 4;                 // class-group base
    const float4* w4 = (const float4*)W2;
    float q0 = 0.0f, q1 = 0.0f, q2 = 0.0f, q3 = 0.0f;
#pragma unroll
    for (int j = 0; j < 16; ++j) {
        float hk = hrow[k0 + 16 * j];     // 16-addr broadcast, conflict-free
        float4 wv = w4[l + 64 * j];       // coalesced: bytes 16l + 1024j
        q0 += hk * wv.x; q1 += hk * wv.y; q2 += hk * wv.z; q3 += hk * wv.w;
    }
#pragma unroll
    for (int o = 4; o <= 32; o <<= 1) {   // reduce lanes sharing (l&3)
        q0 += __shfl_xor(q0, o); q1 += __shfl_xor(q1, o);
        q2 += __shfl_xor(q2, o); q3 += __shfl_xor(q3, o);
    }
    if (l < 4) {                          // lane l owns classes 4l..4l+3
        unsigned u0 = (unsigned)bf16rn(q0) | ((unsigned)bf16rn(q1) << 16);
        unsigned u1 = (unsigned)bf16rn(q2) | ((unsigned)bf16rn(q3) << 16);
        *(uint2*)(xh2b + (size_t)d * NC + 4 * l) = make_uint2(u0, u1);
        float ps = q0 * att_s2[cg] + q1 * att_s2[cg + 1]
                 + q2 * att_s2[cg + 2] + q3 * att_s2[cg + 3];
        float pd = q0 * att_d2[cg] + q1 * att_d2[cg + 1]
                 + q2 * att_d2[cg + 2] + q3 * att_d2[cg + 3];
        ps += __shfl_xor(ps, 1); ps += __shfl_xor(ps, 2);
        pd += __shfl_xor(pd, 1); pd += __shfl_xor(pd, 2);
        if (l == 0) { a_src2[d] = ps; a_dst2[d] = pd; }
    }
}

// ------- layer 2 fused: softmax(no-max) + aggregate + bias + log_softmax -------
// 4 waves/block, 1 dst node per wave; 2 classes/lane, 8 edges in flight
__global__ __launch_bounds__(256) void k_csr2(
        const int* __restrict__ row_start, const int* __restrict__ esrc,
        const float* __restrict__ a_src2, const float* __restrict__ a_dst2,
        const unsigned short* __restrict__ xh2b, const float* __restrict__ b2,
        float* __restrict__ out) {
    int w = threadIdx.x >> 6, l = threadIdx.x & 63;
    int d = blockIdx.x * 4 + w;
    if (d >= N_NODES) return;
    int base = row_start[d], deg = row_start[d + 1] - base;
    __shared__ int   ls[4][64];
    __shared__ float lal[4][64];
    float adh = a_dst2[d];
    int cp = l & 7, je = l >> 3;
    float denl = 0.0f, acc0 = 0.0f, acc1 = 0.0f;
    for (int c0 = 0; c0 < deg; c0 += 64) {
        int cn = min(64, deg - c0);
        if (l < cn) {
            int s = esrc[base + c0 + l];
            ls[w][l] = s;
            float ev = a_src2[s] + adh;
            ev = ev > 0.0f ? ev : SLOPE * ev;
            float wj = __expf(ev);
            lal[w][l] = wj;          // same-wave RAW below
            denl += wj;
        }
        for (int j = je; j < cn; j += 8) {
            float wj = lal[w][j];
            unsigned pv = *(const unsigned*)(xh2b + (size_t)ls[w][j] * NC + 2 * cp);
            acc0 += wj * bf_lo(pv);
            acc1 += wj * bf_hi(pv);
        }
    }
#pragma unroll
    for (int o = 32; o >= 1; o >>= 1) denl += __shfl_xor(denl, o);
#pragma unroll
    for (int o = 8; o <= 32; o <<= 1) {           // reduce over the 8 je slots
        acc0 += __shfl_xor(acc0, o);
        acc1 += __shfl_xor(acc1, o);
    }
    float inv = 1.0f / (denl + 1e-16f);
    float v0 = acc0 * inv + b2[2 * cp];
    float v1 = acc1 * inv + b2[2 * cp + 1];
    float mm = fmaxf(v0, v1);
#pragma unroll
    for (int o = 1; o <= 4; o <<= 1) mm = fmaxf(mm, __shfl_xor(mm, o));
    float se = __expf(v0 - mm) + __expf(v1 - mm);
#pragma unroll
    for (int o = 1; o <= 4; o <<= 1) se += __shfl_xor(se, o);
    float lse = mm + logf(se);
    if (l < 8) *(float2*)(out + (size_t)d * NC + 2 * cp) = make_float2(v0 - lse, v1 - lse);
}

extern "C" void kernel_launch(void* const* d_in, const int* in_sizes, int n_in,
                              void* d_out, int out_size, void* d_ws, size_t ws_size,
                              hipStream_t stream) {
    const float* x        = (const float*)d_in[0];
    const int*   ei       = (const int*)d_in[1];
    const float* W1       = (const float*)d_in[2];
    const float* att_src1 = (const float*)d_in[3];
    const float* att_dst1 = (const float*)d_in[4];
    const float* b1       = (const float*)d_in[5];
    const float* W2       = (const float*)d_in[6];
    const float* att_src2 = (const float*)d_in[7];
    const float* att_dst2 = (const float*)d_in[8];
    const float* b2       = (const float*)d_in[9];
    float* out = (float*)d_out;

    // ---- workspace layout ----
    char* p = (char*)d_ws;
    unsigned short* xh1b  = (unsigned short*)p; p += (size_t)N_NODES * F1 * 2;   // 25.6MB
    unsigned short* xh2b  = (unsigned short*)p; p += (size_t)N_NODES * NC * 2;   // 1.6MB
    float* a_src1 = (float*)p; p += (size_t)N_NODES * HEADS * 4;
    float* a_dst1 = (float*)p; p += (size_t)N_NODES * HEADS * 4;
    float* a_src2 = (float*)p; p += (size_t)N_NODES * 4;
    float* a_dst2 = (float*)p; p += (size_t)N_NODES * 4;
    int* cnt       = (int*)p;  p += (size_t)N_NODES * 4;
    int* cursor    = (int*)p;  p += (size_t)N_NODES * 4;
    int* row_start = (int*)p;  p += (size_t)(N_NODES + 1) * 4;
    int* bsum      = (int*)p;  p += 64 * 4;
    int* esrc      = (int*)p;  p += (size_t)EP * 4;

    // ---- CSR build (hist fused into gemm1) ----
    hipMemsetAsync(cnt, 0, (size_t)N_NODES * 4, stream);
    k_gemm1<<<G1B, 256, 0, stream>>>(x, W1, att_src1, att_dst1, xh1b, a_src1, a_dst1,
                                     ei, cnt);
    k_scan_local<<<NT, 1024, 0, stream>>>(cnt, row_start, bsum);
    k_scan_add<<<(N_NODES + 255) / 256, 256, 0, stream>>>(row_start, bsum, cursor);
    k_scatter<<<(EP + 255) / 256, 256, 0, stream>>>(ei, cursor, esrc);

    // ---- layer 1 (+ fused layer-2 projection), wave-per-node ----
    k_csr1<<<(N_NODES + 3) / 4, 256, 0, stream>>>(row_start, esrc, a_src1, a_dst1, xh1b, b1,
                                                  W2, att_src2, att_dst2, xh2b, a_src2, a_dst2);

    // ---- layer 2 ----
    k_csr2<<<(N_NODES + 3) / 4, 256, 0, stream>>>(row_start, esrc, a_src2, a_dst2, xh2b, b2, out);
}